// Round 7
// baseline (634.547 us; speedup 1.0000x reference)
//
#include <hip/hip_runtime.h>
#include <cstdint>
#include <cstddef>

#define S_TOK 8192
#define MDIM  2048
#define NE    64
#define CAP   128
#define NSEG  256   // 32-token segments

typedef float f32x4 __attribute__((ext_vector_type(4)));

// d_out float layout: [0]=l_aux | [1..+67108864)=combine | [..+67108864)=dispatch | [..+64)=exp_counts
static const size_t COMBINE_OFF  = 1;
static const size_t DISPATCH_OFF = 1 + 67108864ULL;
static const size_t COUNTS_OFF   = 1 + 2ULL * 67108864ULL;   // = 134217729

// LDS-only barrier: orders ds_write -> barrier -> ds_read without draining vmcnt.
__device__ __forceinline__ void bar_lds_only() {
    asm volatile("s_waitcnt lgkmcnt(0)" ::: "memory");
    __builtin_amdgcn_s_barrier();
}

// ---------------------------------------------------------------- shader zero-fill (rocclr recipe)
// Replaces hipMemsetAsync (which the capture lowers to a non-shader fill node running ~4.2 TB/s).
// Exactly the __amd_rocclr_fillBufferAligned structure that measurably sustains 6.27 TB/s on
// this allocation: 2048 blocks x 256 threads (8 blocks/CU = full 32-wave residency),
// grid-interleaved plain dwordx4 stores (iteration i covers one contiguous 8 MB window
// grid-wide), standalone dispatch, no LDS, no barriers, no NT flag.
__global__ __launch_bounds__(256) void k_zero(f32x4* __restrict__ zout,
                                              float* __restrict__ outf) {
    long gid = (long)blockIdx.x * 256 + threadIdx.x;       // 0..524287
    const f32x4 z4 = {0.f, 0.f, 0.f, 0.f};
    #pragma unroll 8
    for (int i = 0; i < 64; ++i)
        zout[(long)i * 524288 + gid] = z4;                 // covers floats [0, 134217728)
    if (gid < 65) outf[134217728 + gid] = 0.f;             // last dispatch float + counts[0..63]
}

// ---------------------------------------------------------------- logits GEMM (split-K=4)
// R4 verbatim. grid (128 row-tiles, 4 k-quarters) = 512 blocks. Tile 64r x 64e, thread 4r x 4e.
// Also zero-inits colsum[64] for softmax atomics.
#define RT 64
#define KC 32
__global__ __launch_bounds__(256) void k_gemm(const float* __restrict__ in,
                                              const float* __restrict__ wg,
                                              float* __restrict__ part,
                                              float* __restrict__ colsum) {
    __shared__ float in_lds[KC][RT + 4];
    __shared__ float wg_lds[KC][NE + 4];
    int t  = threadIdx.x;
    int r0 = blockIdx.x * RT;
    int kbase = blockIdx.y * (MDIM / 4);
    int bid = blockIdx.y * 128 + blockIdx.x;
    if (bid == 0 && t < 64) colsum[t] = 0.f;
    int te = t & 15, tr = t >> 4;
    int kq  = t & 7;
    int row = t >> 3;
    float acc[4][4] = {};
    for (int c = 0; c < 16; ++c) {
        int k0 = kbase + c * KC;
        float4 v0 = *(const float4*)(in + (size_t)(r0 + row) * MDIM + k0 + kq * 4);
        float4 v1 = *(const float4*)(in + (size_t)(r0 + row + 32) * MDIM + k0 + kq * 4);
        float4 w0 = *(const float4*)(wg + (size_t)row * MDIM + k0 + kq * 4);
        float4 w1 = *(const float4*)(wg + (size_t)(row + 32) * MDIM + k0 + kq * 4);
        in_lds[kq * 4 + 0][row] = v0.x; in_lds[kq * 4 + 1][row] = v0.y;
        in_lds[kq * 4 + 2][row] = v0.z; in_lds[kq * 4 + 3][row] = v0.w;
        in_lds[kq * 4 + 0][row + 32] = v1.x; in_lds[kq * 4 + 1][row + 32] = v1.y;
        in_lds[kq * 4 + 2][row + 32] = v1.z; in_lds[kq * 4 + 3][row + 32] = v1.w;
        wg_lds[kq * 4 + 0][row] = w0.x; wg_lds[kq * 4 + 1][row] = w0.y;
        wg_lds[kq * 4 + 2][row] = w0.z; wg_lds[kq * 4 + 3][row] = w0.w;
        wg_lds[kq * 4 + 0][row + 32] = w1.x; wg_lds[kq * 4 + 1][row + 32] = w1.y;
        wg_lds[kq * 4 + 2][row + 32] = w1.z; wg_lds[kq * 4 + 3][row + 32] = w1.w;
        bar_lds_only();
        #pragma unroll
        for (int kk = 0; kk < KC; ++kk) {
            float4 a4 = *(const float4*)&in_lds[kk][tr * 4];
            float4 b4 = *(const float4*)&wg_lds[kk][te * 4];
            float a[4] = {a4.x, a4.y, a4.z, a4.w};
            float b[4] = {b4.x, b4.y, b4.z, b4.w};
            #pragma unroll
            for (int i = 0; i < 4; ++i)
                #pragma unroll
                for (int j = 0; j < 4; ++j)
                    acc[i][j] += a[i] * b[j];
        }
        bar_lds_only();
    }
    #pragma unroll
    for (int i = 0; i < 4; ++i) {
        size_t base = ((size_t)blockIdx.y * S_TOK + r0 + tr * 4 + i) * NE + te * 4;
        *(float4*)(part + base) = make_float4(acc[i][0], acc[i][1], acc[i][2], acc[i][3]);
    }
}

// ---------------------------------------------------------------- softmax + argmax + seg histogram
// R4 verbatim: 256 blocks x 1024 threads (16 waves/CU), 2 rows/wave.
__global__ __launch_bounds__(1024) void k_softmax(const float* __restrict__ part,
                                                  float* __restrict__ colsum,
                                                  float* __restrict__ gate_sel,
                                                  int* __restrict__ eid,
                                                  int* __restrict__ segcnt) {
    __shared__ float ls[NE];
    __shared__ int hist[NE];
    int t = threadIdx.x;
    int lane = t & 63, w = t >> 6;          // w in 0..15
    if (t < NE) { ls[t] = 0.f; hist[t] = 0; }
    __syncthreads();
    float lsum = 0.f;
    #pragma unroll
    for (int i = 0; i < 2; ++i) {
        int r = blockIdx.x * 32 + w * 2 + i;
        float v = part[(size_t)r * NE + lane]
                + part[(size_t)(S_TOK + r) * NE + lane]
                + part[(size_t)(2 * S_TOK + r) * NE + lane]
                + part[(size_t)(3 * S_TOK + r) * NE + lane];
        float m = v; int mi = lane;
        for (int off = 32; off > 0; off >>= 1) {
            float om = __shfl_xor(m, off);
            int   oi = __shfl_xor(mi, off);
            if (om > m || (om == m && oi < mi)) { m = om; mi = oi; }
        }
        float ex = expf(v - m);
        float s = ex;
        for (int off = 32; off > 0; off >>= 1) s += __shfl_xor(s, off);
        float gate = ex / s;
        lsum += gate;
        if (lane == mi) { gate_sel[r] = gate; eid[r] = mi; atomicAdd(&hist[mi], 1); }
    }
    atomicAdd(&ls[lane], lsum);
    __syncthreads();
    if (t < NE) {
        atomicAdd(&colsum[t], ls[t]);
        segcnt[t * NSEG + blockIdx.x] = hist[t];   // [e][seg]
    }
}

// ---------------------------------------------------------------- ranks + scatter + counts + l_aux
// R4 verbatim. Block e: exclusive scan of 256 segment counts, then thread t walks its
// 32-token segment with a running rank, scattering into the zeroed output.
__global__ __launch_bounds__(256) void k_ranks_scatter(const int* __restrict__ eid,
                                                       const float* __restrict__ gate_sel,
                                                       const int* __restrict__ segcnt,
                                                       const float* __restrict__ colsum,
                                                       float* __restrict__ out) {
    __shared__ int wsum[4];
    int e = blockIdx.x;
    int t = threadIdx.x;
    int lane = t & 63, w = t >> 6;
    int c = segcnt[e * NSEG + t];
    // inclusive wave scan
    int incl = c;
    #pragma unroll
    for (int off = 1; off < 64; off <<= 1) {
        int v = __shfl_up(incl, off);
        if (lane >= off) incl += v;
    }
    if (lane == 63) wsum[w] = incl;
    __syncthreads();
    int woff = 0;
    #pragma unroll
    for (int j = 0; j < 4; ++j) if (j < w) woff += wsum[j];
    int excl = woff + incl - c;                    // tokens for e before this segment
    if (t == 0) {
        int total = wsum[0] + wsum[1] + wsum[2] + wsum[3];
        out[COUNTS_OFF + e] = (float)total;
        float term = (colsum[e] / 8192.f) * ((float)total / 8192.f) * 64.f;
        atomicAdd(out, term);                      // l_aux (out[0] zeroed by k_zero)
    }
    if (c == 0 || excl >= CAP) return;             // nothing to write from this segment
    int run = excl;
    int base_s = t * 32;
    #pragma unroll 4
    for (int j = 0; j < 32; ++j) {
        if (run >= CAP) break;
        int s = base_s + j;
        if (eid[s] == e) {
            size_t idx = ((size_t)s * NE + e) * CAP + run;
            out[COMBINE_OFF + idx]  = gate_sel[s];
            out[DISPATCH_OFF + idx] = 1.0f;
            ++run;
        }
    }
}

extern "C" void kernel_launch(void* const* d_in, const int* in_sizes, int n_in,
                              void* d_out, int out_size, void* d_ws, size_t ws_size,
                              hipStream_t stream) {
    const float* in = (const float*)d_in[0];
    const float* wg = (const float*)d_in[1];
    float* out = (float*)d_out;

    float* colsum   = (float*)d_ws;              // 64 f
    float* gate_sel = colsum + 64;               // 8192 f
    int*   eid      = (int*)(gate_sel + 8192);   // 8192 i
    int*   segcnt   = eid + 8192;                // 64*256 i
    float* part     = (float*)(segcnt + NE * NSEG);  // 4*8192*64 f

    k_zero<<<2048, 256, 0, stream>>>((f32x4*)out, out);
    k_gemm<<<dim3(128, 4), 256, 0, stream>>>(in, wg, part, colsum);
    k_softmax<<<256, 1024, 0, stream>>>(part, colsum, gate_sel, eid, segcnt);
    k_ranks_scatter<<<64, 256, 0, stream>>>(eid, gate_sel, segcnt, colsum, out);
}

// Round 8
// 593.172 us; speedup vs baseline: 1.0698x; 1.0698x over previous
//
#include <hip/hip_runtime.h>
#include <cstdint>
#include <cstddef>

#define S_TOK 8192
#define MDIM  2048
#define NE    64
#define CAP   128
#define NSEG  256   // 32-token segments

typedef float f32x4 __attribute__((ext_vector_type(4)));

// d_out float layout: [0]=l_aux | [1..+67108864)=combine | [..+67108864)=dispatch | [..+64)=exp_counts
static const size_t COMBINE_OFF  = 1;
static const size_t DISPATCH_OFF = 1 + 67108864ULL;
static const size_t COUNTS_OFF   = 1 + 2ULL * 67108864ULL;   // = 134217729

// LDS-only barrier: orders ds_write -> barrier -> ds_read without draining vmcnt.
__device__ __forceinline__ void bar_lds_only() {
    asm volatile("s_waitcnt lgkmcnt(0)" ::: "memory");
    __builtin_amdgcn_s_barrier();
}

// ---------------------------------------------------------------- one-store-per-thread zero-fill
// TRUE rocclr fillBufferAligned structure (verified by arithmetic on the harness's poison fill:
// 2.147GB / 256thr / 16B = 524288 workgroups -> ONE 16B store per thread, no loop). Single-store
// waves retire immediately and write in strict dispatch order -> one sequential DRAM write
// stream (row-buffer friendly) instead of 2048 concurrent looped streams (row thrash at
// ~2.5 TB/s, R2/R3/R6/R7). 131072 blocks x 256 threads covers floats [0, 134217728).
__global__ __launch_bounds__(256) void k_fill1(f32x4* __restrict__ zout,
                                               float* __restrict__ outf) {
    long gid = (long)blockIdx.x * 256 + threadIdx.x;       // 0..33554431
    const f32x4 z4 = {0.f, 0.f, 0.f, 0.f};
    zout[gid] = z4;
    if (gid == 0) outf[134217728] = 0.f;   // last dispatch float; counts[0..63] are written
                                           // unconditionally by k_ranks_scatter
}

// ---------------------------------------------------------------- logits GEMM (split-K=4)
// R4 verbatim. grid (128 row-tiles, 4 k-quarters) = 512 blocks. Tile 64r x 64e, thread 4r x 4e.
// Also zero-inits colsum[64] for softmax atomics.
#define RT 64
#define KC 32
__global__ __launch_bounds__(256) void k_gemm(const float* __restrict__ in,
                                              const float* __restrict__ wg,
                                              float* __restrict__ part,
                                              float* __restrict__ colsum) {
    __shared__ float in_lds[KC][RT + 4];
    __shared__ float wg_lds[KC][NE + 4];
    int t  = threadIdx.x;
    int r0 = blockIdx.x * RT;
    int kbase = blockIdx.y * (MDIM / 4);
    int bid = blockIdx.y * 128 + blockIdx.x;
    if (bid == 0 && t < 64) colsum[t] = 0.f;
    int te = t & 15, tr = t >> 4;
    int kq  = t & 7;
    int row = t >> 3;
    float acc[4][4] = {};
    for (int c = 0; c < 16; ++c) {
        int k0 = kbase + c * KC;
        float4 v0 = *(const float4*)(in + (size_t)(r0 + row) * MDIM + k0 + kq * 4);
        float4 v1 = *(const float4*)(in + (size_t)(r0 + row + 32) * MDIM + k0 + kq * 4);
        float4 w0 = *(const float4*)(wg + (size_t)row * MDIM + k0 + kq * 4);
        float4 w1 = *(const float4*)(wg + (size_t)(row + 32) * MDIM + k0 + kq * 4);
        in_lds[kq * 4 + 0][row] = v0.x; in_lds[kq * 4 + 1][row] = v0.y;
        in_lds[kq * 4 + 2][row] = v0.z; in_lds[kq * 4 + 3][row] = v0.w;
        in_lds[kq * 4 + 0][row + 32] = v1.x; in_lds[kq * 4 + 1][row + 32] = v1.y;
        in_lds[kq * 4 + 2][row + 32] = v1.z; in_lds[kq * 4 + 3][row + 32] = v1.w;
        wg_lds[kq * 4 + 0][row] = w0.x; wg_lds[kq * 4 + 1][row] = w0.y;
        wg_lds[kq * 4 + 2][row] = w0.z; wg_lds[kq * 4 + 3][row] = w0.w;
        wg_lds[kq * 4 + 0][row + 32] = w1.x; wg_lds[kq * 4 + 1][row + 32] = w1.y;
        wg_lds[kq * 4 + 2][row + 32] = w1.z; wg_lds[kq * 4 + 3][row + 32] = w1.w;
        bar_lds_only();
        #pragma unroll
        for (int kk = 0; kk < KC; ++kk) {
            float4 a4 = *(const float4*)&in_lds[kk][tr * 4];
            float4 b4 = *(const float4*)&wg_lds[kk][te * 4];
            float a[4] = {a4.x, a4.y, a4.z, a4.w};
            float b[4] = {b4.x, b4.y, b4.z, b4.w};
            #pragma unroll
            for (int i = 0; i < 4; ++i)
                #pragma unroll
                for (int j = 0; j < 4; ++j)
                    acc[i][j] += a[i] * b[j];
        }
        bar_lds_only();
    }
    #pragma unroll
    for (int i = 0; i < 4; ++i) {
        size_t base = ((size_t)blockIdx.y * S_TOK + r0 + tr * 4 + i) * NE + te * 4;
        *(float4*)(part + base) = make_float4(acc[i][0], acc[i][1], acc[i][2], acc[i][3]);
    }
}

// ---------------------------------------------------------------- softmax + argmax + seg histogram
// R4 verbatim: 256 blocks x 1024 threads (16 waves/CU), 2 rows/wave.
__global__ __launch_bounds__(1024) void k_softmax(const float* __restrict__ part,
                                                  float* __restrict__ colsum,
                                                  float* __restrict__ gate_sel,
                                                  int* __restrict__ eid,
                                                  int* __restrict__ segcnt) {
    __shared__ float ls[NE];
    __shared__ int hist[NE];
    int t = threadIdx.x;
    int lane = t & 63, w = t >> 6;          // w in 0..15
    if (t < NE) { ls[t] = 0.f; hist[t] = 0; }
    __syncthreads();
    float lsum = 0.f;
    #pragma unroll
    for (int i = 0; i < 2; ++i) {
        int r = blockIdx.x * 32 + w * 2 + i;
        float v = part[(size_t)r * NE + lane]
                + part[(size_t)(S_TOK + r) * NE + lane]
                + part[(size_t)(2 * S_TOK + r) * NE + lane]
                + part[(size_t)(3 * S_TOK + r) * NE + lane];
        float m = v; int mi = lane;
        for (int off = 32; off > 0; off >>= 1) {
            float om = __shfl_xor(m, off);
            int   oi = __shfl_xor(mi, off);
            if (om > m || (om == m && oi < mi)) { m = om; mi = oi; }
        }
        float ex = expf(v - m);
        float s = ex;
        for (int off = 32; off > 0; off >>= 1) s += __shfl_xor(s, off);
        float gate = ex / s;
        lsum += gate;
        if (lane == mi) { gate_sel[r] = gate; eid[r] = mi; atomicAdd(&hist[mi], 1); }
    }
    atomicAdd(&ls[lane], lsum);
    __syncthreads();
    if (t < NE) {
        atomicAdd(&colsum[t], ls[t]);
        segcnt[t * NSEG + blockIdx.x] = hist[t];   // [e][seg]
    }
}

// ---------------------------------------------------------------- ranks + scatter + counts + l_aux
// R4 verbatim. Block e: exclusive scan of 256 segment counts, then thread t walks its
// 32-token segment with a running rank, scattering into the zeroed output.
__global__ __launch_bounds__(256) void k_ranks_scatter(const int* __restrict__ eid,
                                                       const float* __restrict__ gate_sel,
                                                       const int* __restrict__ segcnt,
                                                       const float* __restrict__ colsum,
                                                       float* __restrict__ out) {
    __shared__ int wsum[4];
    int e = blockIdx.x;
    int t = threadIdx.x;
    int lane = t & 63, w = t >> 6;
    int c = segcnt[e * NSEG + t];
    // inclusive wave scan
    int incl = c;
    #pragma unroll
    for (int off = 1; off < 64; off <<= 1) {
        int v = __shfl_up(incl, off);
        if (lane >= off) incl += v;
    }
    if (lane == 63) wsum[w] = incl;
    __syncthreads();
    int woff = 0;
    #pragma unroll
    for (int j = 0; j < 4; ++j) if (j < w) woff += wsum[j];
    int excl = woff + incl - c;                    // tokens for e before this segment
    if (t == 0) {
        int total = wsum[0] + wsum[1] + wsum[2] + wsum[3];
        out[COUNTS_OFF + e] = (float)total;
        float term = (colsum[e] / 8192.f) * ((float)total / 8192.f) * 64.f;
        atomicAdd(out, term);                      // l_aux (out[0] zeroed by k_fill1)
    }
    if (c == 0 || excl >= CAP) return;             // nothing to write from this segment
    int run = excl;
    int base_s = t * 32;
    #pragma unroll 4
    for (int j = 0; j < 32; ++j) {
        if (run >= CAP) break;
        int s = base_s + j;
        if (eid[s] == e) {
            size_t idx = ((size_t)s * NE + e) * CAP + run;
            out[COMBINE_OFF + idx]  = gate_sel[s];
            out[DISPATCH_OFF + idx] = 1.0f;
            ++run;
        }
    }
}

extern "C" void kernel_launch(void* const* d_in, const int* in_sizes, int n_in,
                              void* d_out, int out_size, void* d_ws, size_t ws_size,
                              hipStream_t stream) {
    const float* in = (const float*)d_in[0];
    const float* wg = (const float*)d_in[1];
    float* out = (float*)d_out;

    float* colsum   = (float*)d_ws;              // 64 f
    float* gate_sel = colsum + 64;               // 8192 f
    int*   eid      = (int*)(gate_sel + 8192);   // 8192 i
    int*   segcnt   = eid + 8192;                // 64*256 i
    float* part     = (float*)(segcnt + NE * NSEG);  // 4*8192*64 f

    k_fill1<<<131072, 256, 0, stream>>>((f32x4*)out, out);
    k_gemm<<<dim3(128, 4), 256, 0, stream>>>(in, wg, part, colsum);
    k_softmax<<<256, 1024, 0, stream>>>(part, colsum, gate_sel, eid, segcnt);
    k_ranks_scatter<<<64, 256, 0, stream>>>(eid, gate_sel, segcnt, colsum, out);
}

// Round 10
// 535.804 us; speedup vs baseline: 1.1843x; 1.1071x over previous
//
#include <hip/hip_runtime.h>
#include <cstdint>
#include <cstddef>

#define S_TOK 8192
#define MDIM  2048
#define NE    64
#define CAP   128
#define NSEG  256   // 32-token segments

typedef float f32x4 __attribute__((ext_vector_type(4)));

// d_out float layout: [0]=l_aux | [1..+67108864)=combine | [..+67108864)=dispatch | [..+64)=exp_counts
static const size_t COMBINE_OFF  = 1;
static const size_t DISPATCH_OFF = 1 + 67108864ULL;
static const size_t COUNTS_OFF   = 1 + 2ULL * 67108864ULL;   // = 134217729

// LDS-only barrier: orders ds_write -> barrier -> ds_read without draining vmcnt.
__device__ __forceinline__ void bar_lds_only() {
    asm volatile("s_waitcnt lgkmcnt(0)" ::: "memory");
    __builtin_amdgcn_s_barrier();
}

// ---------------------------------------------------------------- logits GEMM (split-K=4)
// R4 verbatim. grid (128 row-tiles, 4 k-quarters) = 512 blocks. Tile 64r x 64e, thread 4r x 4e.
// Also zero-inits colsum[64] for softmax atomics.
// NOTE (R9 lesson): split-K reduction MUST stay in a separate dispatch. In-kernel last-block
// reduction fails: sibling partials cross XCDs, and the reader's per-XCD L2 can serve stale
// lines (not invalidated by __threadfence) -> silent argmax flips.
#define RT 64
#define KC 32
__global__ __launch_bounds__(256) void k_gemm(const float* __restrict__ in,
                                              const float* __restrict__ wg,
                                              float* __restrict__ part,
                                              float* __restrict__ colsum) {
    __shared__ float in_lds[KC][RT + 4];
    __shared__ float wg_lds[KC][NE + 4];
    int t  = threadIdx.x;
    int r0 = blockIdx.x * RT;
    int kbase = blockIdx.y * (MDIM / 4);
    int bid = blockIdx.y * 128 + blockIdx.x;
    if (bid == 0 && t < 64) colsum[t] = 0.f;
    int te = t & 15, tr = t >> 4;
    int kq  = t & 7;
    int row = t >> 3;
    float acc[4][4] = {};
    for (int c = 0; c < 16; ++c) {
        int k0 = kbase + c * KC;
        float4 v0 = *(const float4*)(in + (size_t)(r0 + row) * MDIM + k0 + kq * 4);
        float4 v1 = *(const float4*)(in + (size_t)(r0 + row + 32) * MDIM + k0 + kq * 4);
        float4 w0 = *(const float4*)(wg + (size_t)row * MDIM + k0 + kq * 4);
        float4 w1 = *(const float4*)(wg + (size_t)(row + 32) * MDIM + k0 + kq * 4);
        in_lds[kq * 4 + 0][row] = v0.x; in_lds[kq * 4 + 1][row] = v0.y;
        in_lds[kq * 4 + 2][row] = v0.z; in_lds[kq * 4 + 3][row] = v0.w;
        in_lds[kq * 4 + 0][row + 32] = v1.x; in_lds[kq * 4 + 1][row + 32] = v1.y;
        in_lds[kq * 4 + 2][row + 32] = v1.z; in_lds[kq * 4 + 3][row + 32] = v1.w;
        wg_lds[kq * 4 + 0][row] = w0.x; wg_lds[kq * 4 + 1][row] = w0.y;
        wg_lds[kq * 4 + 2][row] = w0.z; wg_lds[kq * 4 + 3][row] = w0.w;
        wg_lds[kq * 4 + 0][row + 32] = w1.x; wg_lds[kq * 4 + 1][row + 32] = w1.y;
        wg_lds[kq * 4 + 2][row + 32] = w1.z; wg_lds[kq * 4 + 3][row + 32] = w1.w;
        bar_lds_only();
        #pragma unroll
        for (int kk = 0; kk < KC; ++kk) {
            float4 a4 = *(const float4*)&in_lds[kk][tr * 4];
            float4 b4 = *(const float4*)&wg_lds[kk][te * 4];
            float a[4] = {a4.x, a4.y, a4.z, a4.w};
            float b[4] = {b4.x, b4.y, b4.z, b4.w};
            #pragma unroll
            for (int i = 0; i < 4; ++i)
                #pragma unroll
                for (int j = 0; j < 4; ++j)
                    acc[i][j] += a[i] * b[j];
        }
        bar_lds_only();
    }
    #pragma unroll
    for (int i = 0; i < 4; ++i) {
        size_t base = ((size_t)blockIdx.y * S_TOK + r0 + tr * 4 + i) * NE + te * 4;
        *(float4*)(part + base) = make_float4(acc[i][0], acc[i][1], acc[i][2], acc[i][3]);
    }
}

// ---------------------------------------------------------------- softmax + argmax + seg histogram
// R4 verbatim: 256 blocks x 1024 threads (16 waves/CU), 2 rows/wave.
__global__ __launch_bounds__(1024) void k_softmax(const float* __restrict__ part,
                                                  float* __restrict__ colsum,
                                                  float* __restrict__ gate_sel,
                                                  int* __restrict__ eid,
                                                  int* __restrict__ segcnt) {
    __shared__ float ls[NE];
    __shared__ int hist[NE];
    int t = threadIdx.x;
    int lane = t & 63, w = t >> 6;          // w in 0..15
    if (t < NE) { ls[t] = 0.f; hist[t] = 0; }
    __syncthreads();
    float lsum = 0.f;
    #pragma unroll
    for (int i = 0; i < 2; ++i) {
        int r = blockIdx.x * 32 + w * 2 + i;
        float v = part[(size_t)r * NE + lane]
                + part[(size_t)(S_TOK + r) * NE + lane]
                + part[(size_t)(2 * S_TOK + r) * NE + lane]
                + part[(size_t)(3 * S_TOK + r) * NE + lane];
        float m = v; int mi = lane;
        for (int off = 32; off > 0; off >>= 1) {
            float om = __shfl_xor(m, off);
            int   oi = __shfl_xor(mi, off);
            if (om > m || (om == m && oi < mi)) { m = om; mi = oi; }
        }
        float ex = expf(v - m);
        float s = ex;
        for (int off = 32; off > 0; off >>= 1) s += __shfl_xor(s, off);
        float gate = ex / s;
        lsum += gate;
        if (lane == mi) { gate_sel[r] = gate; eid[r] = mi; atomicAdd(&hist[mi], 1); }
    }
    atomicAdd(&ls[lane], lsum);
    __syncthreads();
    if (t < NE) {
        atomicAdd(&colsum[t], ls[t]);
        segcnt[t * NSEG + blockIdx.x] = hist[t];   // [e][seg]
    }
}

// ---------------------------------------------------------------- ranks + scatter + counts + l_aux
// R4 verbatim. Block e: exclusive scan of 256 segment counts, then thread t walks its
// 32-token segment with a running rank, scattering into the memset-zeroed output.
__global__ __launch_bounds__(256) void k_ranks_scatter(const int* __restrict__ eid,
                                                       const float* __restrict__ gate_sel,
                                                       const int* __restrict__ segcnt,
                                                       const float* __restrict__ colsum,
                                                       float* __restrict__ out) {
    __shared__ int wsum[4];
    int e = blockIdx.x;
    int t = threadIdx.x;
    int lane = t & 63, w = t >> 6;
    int c = segcnt[e * NSEG + t];
    // inclusive wave scan
    int incl = c;
    #pragma unroll
    for (int off = 1; off < 64; off <<= 1) {
        int v = __shfl_up(incl, off);
        if (lane >= off) incl += v;
    }
    if (lane == 63) wsum[w] = incl;
    __syncthreads();
    int woff = 0;
    #pragma unroll
    for (int j = 0; j < 4; ++j) if (j < w) woff += wsum[j];
    int excl = woff + incl - c;                    // tokens for e before this segment
    if (t == 0) {
        int total = wsum[0] + wsum[1] + wsum[2] + wsum[3];
        out[COUNTS_OFF + e] = (float)total;
        float term = (colsum[e] / 8192.f) * ((float)total / 8192.f) * 64.f;
        atomicAdd(out, term);                      // l_aux (out[0] zeroed by memset)
    }
    if (c == 0 || excl >= CAP) return;             // nothing to write from this segment
    int run = excl;
    int base_s = t * 32;
    #pragma unroll 4
    for (int j = 0; j < 32; ++j) {
        if (run >= CAP) break;
        int s = base_s + j;
        if (eid[s] == e) {
            size_t idx = ((size_t)s * NE + e) * CAP + run;
            out[COMBINE_OFF + idx]  = gate_sel[s];
            out[DISPATCH_OFF + idx] = 1.0f;
            ++run;
        }
    }
}

extern "C" void kernel_launch(void* const* d_in, const int* in_sizes, int n_in,
                              void* d_out, int out_size, void* d_ws, size_t ws_size,
                              hipStream_t stream) {
    const float* in = (const float*)d_in[0];
    const float* wg = (const float*)d_in[1];
    float* out = (float*)d_out;

    float* colsum   = (float*)d_ws;              // 64 f
    float* gate_sel = colsum + 64;               // 8192 f
    int*   eid      = (int*)(gate_sel + 8192);   // 8192 i
    int*   segcnt   = eid + 8192;                // 64*256 i
    float* part     = (float*)(segcnt + NE * NSEG);  // 4*8192*64 f

    // Zero the whole output via the memset path (best measured fill: 538 vs shader fills 593-643).
    hipMemsetAsync(d_out, 0, (size_t)out_size, stream);
    k_gemm<<<dim3(128, 4), 256, 0, stream>>>(in, wg, part, colsum);
    k_softmax<<<256, 1024, 0, stream>>>(part, colsum, gate_sel, eid, segcnt);
    k_ranks_scatter<<<64, 256, 0, stream>>>(eid, gate_sel, segcnt, colsum, out);
}